// Round 3
// baseline (374.142 us; speedup 1.0000x reference)
//
#include <hip/hip_runtime.h>
#include <math.h>

// Problem constants (from reference)
#define NN 20000          // nodes
#define TT 4              // time steps
#define EE 320000         // edges
#define NT (NN*TT)        // 80000 rows
#define H1 8              // heads layer 1
#define F1 16             // feat per head layer 1
#define C1 (H1*F1)        // 128
#define IN_F 32
#define OUT_F 16

// ---------------------------------------------------------------------------
// Pass A: feat1 = x @ W1  [NT,128]; el1/er1 = head-dots  [NT,8]
// Block: 256 threads, 16 rows per block (each thread: 8 rows x 1 col).
// ---------------------------------------------------------------------------
__global__ __launch_bounds__(256) void k_feat1(
    const float* __restrict__ x, const float* __restrict__ W1,
    const float* __restrict__ al1, const float* __restrict__ ar1,
    float* __restrict__ feat1, float* __restrict__ el1, float* __restrict__ er1) {
  __shared__ float Ws[IN_F * C1];     // 4096 floats
  __shared__ float xs[16][IN_F + 1];  // padded
  int tid = threadIdx.x;
#pragma unroll
  for (int i = 0; i < 16; ++i) Ws[tid + 256 * i] = W1[tid + 256 * i];
  int base = blockIdx.x * 16;
#pragma unroll
  for (int i = 0; i < 2; ++i) {
    int j = tid + 256 * i;            // 0..511
    int rr = j >> 5, kk = j & 31;
    xs[rr][kk] = x[(base + rr) * IN_F + kk];
  }
  __syncthreads();
  int col = tid & 127;
  int rhalf = tid >> 7;               // 0..1
  float acc[8];
#pragma unroll
  for (int q = 0; q < 8; ++q) acc[q] = 0.f;
#pragma unroll
  for (int k = 0; k < IN_F; ++k) {
    float w = Ws[k * C1 + col];
#pragma unroll
    for (int q = 0; q < 8; ++q) acc[q] = fmaf(xs[q * 2 + rhalf][k], w, acc[q]);
  }
  float alv = al1[col], arv = ar1[col];
  int hh = col >> 4;
#pragma unroll
  for (int q = 0; q < 8; ++q) {
    int row = base + q * 2 + rhalf;
    feat1[row * C1 + col] = acc[q];
    float ev = acc[q] * alv;
    float rv = acc[q] * arv;
#pragma unroll
    for (int m = 8; m >= 1; m >>= 1) {
      ev += __shfl_xor(ev, m);
      rv += __shfl_xor(rv, m);
    }
    if ((col & 15) == 0) {
      el1[row * H1 + hh] = ev;
      er1[row * H1 + hh] = rv;
    }
  }
}

// ---------------------------------------------------------------------------
// CSR build: counts -> exclusive scan -> scatter (src+dst in CSR order)
// ---------------------------------------------------------------------------
__global__ void k_count(const int* __restrict__ dst, int* __restrict__ counts) {
  int e = blockIdx.x * 256 + threadIdx.x;
  if (e < EE) atomicAdd(&counts[dst[e]], 1);
}

// Single block, 1024 threads x 20 serial elements + one 1024-wide LDS scan.
__global__ __launch_bounds__(1024) void k_scan(
    const int* __restrict__ counts, int* __restrict__ offs,
    int* __restrict__ cursor) {
  __shared__ int sums[1024];
  int tid = threadIdx.x;
  int base = tid * 20;
  int local[20];
  int run = 0;
#pragma unroll
  for (int j = 0; j < 20; ++j) {
    int i = base + j;
    int v = (i < NN) ? counts[i] : 0;
    local[j] = run;                   // exclusive prefix within thread
    run += v;
  }
  sums[tid] = run;
  __syncthreads();
  int val = run;
#pragma unroll
  for (int off = 1; off < 1024; off <<= 1) {
    int add = (tid >= off) ? sums[tid - off] : 0;
    __syncthreads();
    val += add;
    sums[tid] = val;
    __syncthreads();
  }
  int excl = val - run;               // exclusive prefix at thread base
#pragma unroll
  for (int j = 0; j < 20; ++j) {
    int i = base + j;
    if (i < NN) {
      int o = excl + local[j];
      offs[i] = o;
      cursor[i] = o;
    }
  }
  if (tid == 1023) offs[NN] = val;    // == EE
}

__global__ void k_scatter(const int* __restrict__ src, const int* __restrict__ dst,
                          int* __restrict__ cursor, int* __restrict__ csr_src,
                          int* __restrict__ csr_dst) {
  int e = blockIdx.x * 256 + threadIdx.x;
  if (e < EE) {
    int d = dst[e];
    int pos = atomicAdd(&cursor[d], 1);
    csr_src[pos] = src[e];
    csr_dst[pos] = d;
  }
}

// ---------------------------------------------------------------------------
// Edge pass 1: p1[i][t][h] = exp(leakyrelu(el1[src] + er1[dst])), CSR order.
// One thread per (edge, t, h): EE*32 threads, fully coalesced row gathers.
// ---------------------------------------------------------------------------
__global__ __launch_bounds__(256) void k_edge1(
    const float* __restrict__ el1, const float* __restrict__ er1,
    const int* __restrict__ csr_src, const int* __restrict__ csr_dst,
    float* __restrict__ p1) {
  int gid = blockIdx.x * 256 + threadIdx.x;   // i*32 + th
  int i = gid >> 5, th = gid & 31;
  int s = csr_src[i], d = csr_dst[i];
  float e = el1[s * 32 + th] + er1[d * 32 + th];
  e = (e >= 0.f) ? e : 0.2f * e;
  p1[gid] = __expf(e);
}

// ---------------------------------------------------------------------------
// Pass C: layer-1 aggregate. One block per dst node; 512 threads = (t,c).
// Inner loop: shfl src + p1 stream-load + feat gather + fma, 4x unrolled.
// ---------------------------------------------------------------------------
__global__ __launch_bounds__(512) void k_agg1(
    const float* __restrict__ feat1, const float* __restrict__ p1,
    const int* __restrict__ offs, const int* __restrict__ csr_src,
    const float* __restrict__ b1, float* __restrict__ h) {
  int n = blockIdx.x;
  int tid = threadIdx.x;
  int t = tid >> 7, c = tid & 127, hh = c >> 4;
  int th = t * 8 + hh;
  int base_tc = t * C1 + c;
  int lane = tid & 63;
  int beg = offs[n], end = offs[n + 1];
  float l = 0.f, acc = 0.f;
  for (int chunk = beg; chunk < end; chunk += 64) {
    int m = min(64, end - chunk);
    int sv = (lane < m) ? csr_src[chunk + lane] : 0;
    const float* pp = p1 + (size_t)chunk * 32 + th;
    int j = 0;
    for (; j + 4 <= m; j += 4) {
      int s0 = __shfl(sv, j);
      int s1 = __shfl(sv, j + 1);
      int s2 = __shfl(sv, j + 2);
      int s3 = __shfl(sv, j + 3);
      float w0 = pp[(j + 0) * 32];
      float w1 = pp[(j + 1) * 32];
      float w2 = pp[(j + 2) * 32];
      float w3 = pp[(j + 3) * 32];
      float f0 = feat1[s0 * 512 + base_tc];
      float f1 = feat1[s1 * 512 + base_tc];
      float f2 = feat1[s2 * 512 + base_tc];
      float f3 = feat1[s3 * 512 + base_tc];
      l += (w0 + w1) + (w2 + w3);
      acc = fmaf(w0, f0, acc);
      acc = fmaf(w1, f1, acc);
      acc = fmaf(w2, f2, acc);
      acc = fmaf(w3, f3, acc);
    }
    for (; j < m; ++j) {
      int s0 = __shfl(sv, j);
      float w0 = pp[j * 32];
      l += w0;
      acc = fmaf(w0, feat1[s0 * 512 + base_tc], acc);
    }
  }
  float r = (l > 0.f) ? (acc / l) : 0.f;
  h[(n * TT + t) * C1 + c] = r + b1[c];
}

// ---------------------------------------------------------------------------
// Pass D: feat2 = h @ W2 [NT,16]; el2/er2 [NT]
// ---------------------------------------------------------------------------
__global__ __launch_bounds__(256) void k_feat2(
    const float* __restrict__ h, const float* __restrict__ W2,
    const float* __restrict__ al2, const float* __restrict__ ar2,
    float* __restrict__ feat2, float* __restrict__ el2, float* __restrict__ er2) {
  __shared__ float Ws[C1 * OUT_F];    // 2048 floats
  __shared__ float hs[16 * 132];      // padded stride
  int tid = threadIdx.x;
#pragma unroll
  for (int i = 0; i < 8; ++i) Ws[tid + 256 * i] = W2[tid + 256 * i];
  int base = blockIdx.x * 16;
#pragma unroll
  for (int i = 0; i < 8; ++i) {
    int j = tid + 256 * i;            // 0..2047
    int rr = j >> 7, kk = j & 127;
    hs[rr * 132 + kk] = h[(base + rr) * C1 + kk];
  }
  __syncthreads();
  int r = tid >> 4, col = tid & 15;
  float acc = 0.f;
#pragma unroll
  for (int k = 0; k < C1; ++k) acc = fmaf(hs[r * 132 + k], Ws[k * OUT_F + col], acc);
  int row = base + r;
  feat2[row * OUT_F + col] = acc;
  float ev = acc * al2[col];
  float rv = acc * ar2[col];
#pragma unroll
  for (int m = 8; m >= 1; m >>= 1) {
    ev += __shfl_xor(ev, m);
    rv += __shfl_xor(rv, m);
  }
  if (col == 0) {
    el2[row] = ev;
    er2[row] = rv;
  }
}

// ---------------------------------------------------------------------------
// Edge pass 2: p2[i][t] = exp(leakyrelu(el2[src] + er2[dst])), CSR order.
// ---------------------------------------------------------------------------
__global__ __launch_bounds__(256) void k_edge2(
    const float* __restrict__ el2, const float* __restrict__ er2,
    const int* __restrict__ csr_src, const int* __restrict__ csr_dst,
    float* __restrict__ p2) {
  int gid = blockIdx.x * 256 + threadIdx.x;   // i*4 + t
  int i = gid >> 2, t = gid & 3;
  int s = csr_src[i], d = csr_dst[i];
  float e = el2[s * 4 + t] + er2[d * 4 + t];
  e = (e >= 0.f) ? e : 0.2f * e;
  p2[gid] = __expf(e);
}

// ---------------------------------------------------------------------------
// Pass E: layer-2 aggregate. 4 nodes per 256-thread block; one wave per node.
// ---------------------------------------------------------------------------
__global__ __launch_bounds__(256) void k_agg2(
    const float* __restrict__ feat2, const float* __restrict__ p2,
    const int* __restrict__ offs, const int* __restrict__ csr_src,
    const float* __restrict__ b2, float* __restrict__ out) {
  int tid = threadIdx.x;
  int n = blockIdx.x * 4 + (tid >> 6);
  int lane = tid & 63, t = lane >> 4, f = lane & 15;
  int base_tf = t * OUT_F + f;
  int beg = offs[n], end = offs[n + 1];
  float l = 0.f, acc = 0.f;
  for (int chunk = beg; chunk < end; chunk += 64) {
    int m = min(64, end - chunk);
    int sv = (lane < m) ? csr_src[chunk + lane] : 0;
    const float* pp = p2 + (size_t)chunk * 4 + t;
    int j = 0;
    for (; j + 4 <= m; j += 4) {
      int s0 = __shfl(sv, j);
      int s1 = __shfl(sv, j + 1);
      int s2 = __shfl(sv, j + 2);
      int s3 = __shfl(sv, j + 3);
      float w0 = pp[(j + 0) * 4];
      float w1 = pp[(j + 1) * 4];
      float w2 = pp[(j + 2) * 4];
      float w3 = pp[(j + 3) * 4];
      float f0 = feat2[s0 * 64 + base_tf];
      float f1 = feat2[s1 * 64 + base_tf];
      float f2 = feat2[s2 * 64 + base_tf];
      float f3 = feat2[s3 * 64 + base_tf];
      l += (w0 + w1) + (w2 + w3);
      acc = fmaf(w0, f0, acc);
      acc = fmaf(w1, f1, acc);
      acc = fmaf(w2, f2, acc);
      acc = fmaf(w3, f3, acc);
    }
    for (; j < m; ++j) {
      int s0 = __shfl(sv, j);
      float w0 = pp[j * 4];
      l += w0;
      acc = fmaf(w0, feat2[s0 * 64 + base_tf], acc);
    }
  }
  float r = (l > 0.f) ? (acc / l) : 0.f;
  out[(n * TT + t) * OUT_F + f] = r + b2[f];
}

// ---------------------------------------------------------------------------
extern "C" void kernel_launch(void* const* d_in, const int* in_sizes, int n_in,
                              void* d_out, int out_size, void* d_ws, size_t ws_size,
                              hipStream_t stream) {
  const float* x   = (const float*)d_in[0];
  const int*   src = (const int*)d_in[1];
  const int*   dst = (const int*)d_in[2];
  const float* W1  = (const float*)d_in[3];
  const float* al1 = (const float*)d_in[4];
  const float* ar1 = (const float*)d_in[5];
  const float* b1  = (const float*)d_in[6];
  const float* W2  = (const float*)d_in[7];
  const float* al2 = (const float*)d_in[8];
  const float* ar2 = (const float*)d_in[9];
  const float* b2  = (const float*)d_in[10];
  float* out = (float*)d_out;

  // Workspace layout (floats), ~137 MB total
  float* ws    = (float*)d_ws;
  float* feat1 = ws;                           // NT*128
  float* el1   = feat1 + (size_t)NT * C1;      // NT*8
  float* er1   = el1 + (size_t)NT * H1;        // NT*8
  float* h     = er1 + (size_t)NT * H1;        // NT*128
  float* feat2 = h + (size_t)NT * C1;          // NT*16
  float* el2   = feat2 + (size_t)NT * OUT_F;   // NT
  float* er2   = el2 + NT;                     // NT
  float* p1    = er2 + NT;                     // EE*32
  float* p2    = feat1;                        // EE*4, aliases feat1 (dead after k_agg1)
  int* counts  = (int*)(p1 + (size_t)EE * 32); // NN
  int* offs    = counts + NN;                  // NN+1 (pad to NN+4)
  int* cursor  = offs + NN + 4;                // NN
  int* csr_src = cursor + NN;                  // EE
  int* csr_dst = csr_src + EE;                 // EE

  hipMemsetAsync(counts, 0, NN * sizeof(int), stream);

  k_feat1<<<NT / 16, 256, 0, stream>>>(x, W1, al1, ar1, feat1, el1, er1);
  k_count<<<EE / 256, 256, 0, stream>>>(dst, counts);
  k_scan<<<1, 1024, 0, stream>>>(counts, offs, cursor);
  k_scatter<<<EE / 256, 256, 0, stream>>>(src, dst, cursor, csr_src, csr_dst);
  k_edge1<<<EE * 32 / 256, 256, 0, stream>>>(el1, er1, csr_src, csr_dst, p1);
  k_agg1<<<NN, 512, 0, stream>>>(feat1, p1, offs, csr_src, b1, h);
  k_feat2<<<NT / 16, 256, 0, stream>>>(h, W2, al2, ar2, feat2, el2, er2);
  k_edge2<<<EE * 4 / 256, 256, 0, stream>>>(el2, er2, csr_src, csr_dst, p2);
  k_agg2<<<NN / 4, 256, 0, stream>>>(feat2, p2, offs, csr_src, b2, out);
}

// Round 4
// 303.009 us; speedup vs baseline: 1.2348x; 1.2348x over previous
//
#include <hip/hip_runtime.h>
#include <hip/hip_fp16.h>
#include <math.h>

// Problem constants (from reference)
#define NN 20000          // nodes
#define TT 4              // time steps
#define EE 320000         // edges
#define NT (NN*TT)        // 80000 rows
#define H1 8              // heads layer 1
#define C1 128            // heads*f_out layer 1
#define IN_F 32
#define OUT_F 16

__device__ __forceinline__ float lrelu_exp(float e) {
  e = (e >= 0.f) ? e : 0.2f * e;
  return __expf(e);
}

// ---------------------------------------------------------------------------
// Pass A: feat1 = x @ W1 -> fp16 [NT,128]; el1/er1 = head-dots fp32 [NT,8]
// Block: 256 threads, 16 rows per block (each thread: 8 rows x 1 col).
// ---------------------------------------------------------------------------
__global__ __launch_bounds__(256) void k_feat1(
    const float* __restrict__ x, const float* __restrict__ W1,
    const float* __restrict__ al1, const float* __restrict__ ar1,
    __half* __restrict__ feat1h, float* __restrict__ el1, float* __restrict__ er1) {
  __shared__ float Ws[IN_F * C1];     // 4096 floats
  __shared__ float xs[16][IN_F + 1];  // padded
  int tid = threadIdx.x;
#pragma unroll
  for (int i = 0; i < 16; ++i) Ws[tid + 256 * i] = W1[tid + 256 * i];
  int base = blockIdx.x * 16;
#pragma unroll
  for (int i = 0; i < 2; ++i) {
    int j = tid + 256 * i;            // 0..511
    int rr = j >> 5, kk = j & 31;
    xs[rr][kk] = x[(base + rr) * IN_F + kk];
  }
  __syncthreads();
  int col = tid & 127;
  int rhalf = tid >> 7;               // 0..1
  float acc[8];
#pragma unroll
  for (int q = 0; q < 8; ++q) acc[q] = 0.f;
#pragma unroll
  for (int k = 0; k < IN_F; ++k) {
    float w = Ws[k * C1 + col];
#pragma unroll
    for (int q = 0; q < 8; ++q) acc[q] = fmaf(xs[q * 2 + rhalf][k], w, acc[q]);
  }
  float alv = al1[col], arv = ar1[col];
  int hh = col >> 4;
#pragma unroll
  for (int q = 0; q < 8; ++q) {
    int row = base + q * 2 + rhalf;
    feat1h[row * C1 + col] = __float2half(acc[q]);
    float ev = acc[q] * alv;
    float rv = acc[q] * arv;
#pragma unroll
    for (int m = 8; m >= 1; m >>= 1) {
      ev += __shfl_xor(ev, m);
      rv += __shfl_xor(rv, m);
    }
    if ((col & 15) == 0) {
      el1[row * H1 + hh] = ev;
      er1[row * H1 + hh] = rv;
    }
  }
}

// ---------------------------------------------------------------------------
// CSR build: counts -> exclusive scan -> scatter (src in CSR order)
// ---------------------------------------------------------------------------
__global__ void k_count(const int* __restrict__ dst, int* __restrict__ counts) {
  int e = blockIdx.x * 256 + threadIdx.x;
  if (e < EE) atomicAdd(&counts[dst[e]], 1);
}

__global__ __launch_bounds__(1024) void k_scan(
    const int* __restrict__ counts, int* __restrict__ offs,
    int* __restrict__ cursor) {
  __shared__ int sums[1024];
  int tid = threadIdx.x;
  int base = tid * 20;
  int local[20];
  int run = 0;
#pragma unroll
  for (int j = 0; j < 20; ++j) {
    int i = base + j;
    int v = (i < NN) ? counts[i] : 0;
    local[j] = run;                   // exclusive prefix within thread
    run += v;
  }
  sums[tid] = run;
  __syncthreads();
  int val = run;
#pragma unroll
  for (int off = 1; off < 1024; off <<= 1) {
    int add = (tid >= off) ? sums[tid - off] : 0;
    __syncthreads();
    val += add;
    sums[tid] = val;
    __syncthreads();
  }
  int excl = val - run;
#pragma unroll
  for (int j = 0; j < 20; ++j) {
    int i = base + j;
    if (i < NN) {
      int o = excl + local[j];
      offs[i] = o;
      cursor[i] = o;
    }
  }
  if (tid == 1023) offs[NN] = val;    // == EE
}

__global__ void k_scatter(const int* __restrict__ src, const int* __restrict__ dst,
                          int* __restrict__ cursor, int* __restrict__ csr_src) {
  int e = blockIdx.x * 256 + threadIdx.x;
  if (e < EE) {
    int d = dst[e];
    int pos = atomicAdd(&cursor[d], 1);
    csr_src[pos] = src[e];
  }
}

// ---------------------------------------------------------------------------
// Pass C: layer-1 softmax-aggregate. One block per dst node; 256 threads =
// 4 waves (one per t), lane handles channels {2*lane, 2*lane+1} (fp16x2).
// Per 64-edge chunk each lane computes the 8 head-weights for ITS edge
// (float4x2 el1 load, exp x8) into a wave-private LDS tile (no barrier);
// consumers ds_read the broadcast weight. No global p traffic.
// ---------------------------------------------------------------------------
__global__ __launch_bounds__(256) void k_agg1(
    const __half2* __restrict__ feat1h2,   // [NT][64] half2
    const float* __restrict__ el1, const float* __restrict__ er1,
    const int* __restrict__ offs, const int* __restrict__ csr_src,
    const float* __restrict__ b1, float* __restrict__ h) {
  __shared__ float plds[4][64][8];         // 8 KB, wave-private slabs
  int n = blockIdx.x;
  int tid = threadIdx.x;
  int t = tid >> 6;                        // wave id == t
  int lane = tid & 63;
  int hh = lane >> 3;                      // head for this lane's channel pair
  int beg = offs[n], end = offs[n + 1];
  float4 erA = *(const float4*)&er1[(n * TT + t) * H1];
  float4 erB = *(const float4*)&er1[(n * TT + t) * H1 + 4];
  float* myp = &plds[t][0][0];
  float l = 0.f;
  float accx = 0.f, accy = 0.f;
  for (int chunk = beg; chunk < end; chunk += 64) {
    int m = min(64, end - chunk);
    int sv = 0;
    if (lane < m) {
      sv = csr_src[chunk + lane];
      const float4* e4 = (const float4*)&el1[(sv * TT + t) * H1];
      float4 ea = e4[0], eb = e4[1];
      float4 w0, w1;
      w0.x = lrelu_exp(ea.x + erA.x);
      w0.y = lrelu_exp(ea.y + erA.y);
      w0.z = lrelu_exp(ea.z + erA.z);
      w0.w = lrelu_exp(ea.w + erA.w);
      w1.x = lrelu_exp(eb.x + erB.x);
      w1.y = lrelu_exp(eb.y + erB.y);
      w1.z = lrelu_exp(eb.z + erB.z);
      w1.w = lrelu_exp(eb.w + erB.w);
      *(float4*)&myp[lane * 8]     = w0;
      *(float4*)&myp[lane * 8 + 4] = w1;
    }
    // wave-private LDS: same wave wrote it, lgkmcnt ordering suffices
    int j = 0;
    for (; j + 4 <= m; j += 4) {
      int s0 = __shfl(sv, j);
      int s1 = __shfl(sv, j + 1);
      int s2 = __shfl(sv, j + 2);
      int s3 = __shfl(sv, j + 3);
      float w0 = myp[(j + 0) * 8 + hh];
      float w1 = myp[(j + 1) * 8 + hh];
      float w2 = myp[(j + 2) * 8 + hh];
      float w3 = myp[(j + 3) * 8 + hh];
      __half2 f0 = feat1h2[(s0 * TT + t) * 64 + lane];
      __half2 f1 = feat1h2[(s1 * TT + t) * 64 + lane];
      __half2 f2 = feat1h2[(s2 * TT + t) * 64 + lane];
      __half2 f3 = feat1h2[(s3 * TT + t) * 64 + lane];
      float2 g0 = __half22float2(f0);
      float2 g1 = __half22float2(f1);
      float2 g2 = __half22float2(f2);
      float2 g3 = __half22float2(f3);
      l += (w0 + w1) + (w2 + w3);
      accx = fmaf(w0, g0.x, accx); accy = fmaf(w0, g0.y, accy);
      accx = fmaf(w1, g1.x, accx); accy = fmaf(w1, g1.y, accy);
      accx = fmaf(w2, g2.x, accx); accy = fmaf(w2, g2.y, accy);
      accx = fmaf(w3, g3.x, accx); accy = fmaf(w3, g3.y, accy);
    }
    for (; j < m; ++j) {
      int s0 = __shfl(sv, j);
      float w0 = myp[j * 8 + hh];
      float2 g0 = __half22float2(feat1h2[(s0 * TT + t) * 64 + lane]);
      l += w0;
      accx = fmaf(w0, g0.x, accx);
      accy = fmaf(w0, g0.y, accy);
    }
  }
  float inv = (l > 0.f) ? (1.f / l) : 0.f;
  float2 bv = *(const float2*)&b1[2 * lane];
  float2 r;
  r.x = accx * inv + bv.x;
  r.y = accy * inv + bv.y;
  *(float2*)&h[(n * TT + t) * C1 + 2 * lane] = r;
}

// ---------------------------------------------------------------------------
// Pass D: feat2 = h @ W2 -> fp16 [NT,16]; el2/er2 fp32 [NT]
// ---------------------------------------------------------------------------
__global__ __launch_bounds__(256) void k_feat2(
    const float* __restrict__ h, const float* __restrict__ W2,
    const float* __restrict__ al2, const float* __restrict__ ar2,
    __half* __restrict__ feat2h, float* __restrict__ el2, float* __restrict__ er2) {
  __shared__ float Ws[C1 * OUT_F];    // 2048 floats
  __shared__ float hs[16 * 132];      // padded stride
  int tid = threadIdx.x;
#pragma unroll
  for (int i = 0; i < 8; ++i) Ws[tid + 256 * i] = W2[tid + 256 * i];
  int base = blockIdx.x * 16;
#pragma unroll
  for (int i = 0; i < 8; ++i) {
    int j = tid + 256 * i;            // 0..2047
    int rr = j >> 7, kk = j & 127;
    hs[rr * 132 + kk] = h[(base + rr) * C1 + kk];
  }
  __syncthreads();
  int r = tid >> 4, col = tid & 15;
  float acc = 0.f;
#pragma unroll
  for (int k = 0; k < C1; ++k) acc = fmaf(hs[r * 132 + k], Ws[k * OUT_F + col], acc);
  int row = base + r;
  feat2h[row * OUT_F + col] = __float2half(acc);
  float ev = acc * al2[col];
  float rv = acc * ar2[col];
#pragma unroll
  for (int m = 8; m >= 1; m >>= 1) {
    ev += __shfl_xor(ev, m);
    rv += __shfl_xor(rv, m);
  }
  if (col == 0) {
    el2[row] = ev;
    er2[row] = rv;
  }
}

// ---------------------------------------------------------------------------
// Pass E: layer-2 aggregate. 4 nodes per 256-thread block; one wave per node
// = (t,f) = (4,16). Same wave-private LDS weight scheme (4 exps/lane/chunk).
// ---------------------------------------------------------------------------
__global__ __launch_bounds__(256) void k_agg2(
    const __half* __restrict__ feat2h,     // [NT][16] = [s][64 halves]
    const float* __restrict__ el2, const float* __restrict__ er2,
    const int* __restrict__ offs, const int* __restrict__ csr_src,
    const float* __restrict__ b2, float* __restrict__ out) {
  __shared__ float plds[4][64][4];         // 4 KB, wave-private slabs
  int tid = threadIdx.x;
  int nb = tid >> 6;
  int n = blockIdx.x * 4 + nb;
  int lane = tid & 63, t = lane >> 4, f = lane & 15;
  int beg = offs[n], end = offs[n + 1];
  float4 ern = *(const float4*)&er2[n * TT];
  float* myp = &plds[nb][0][0];
  float l = 0.f, acc = 0.f;
  for (int chunk = beg; chunk < end; chunk += 64) {
    int m = min(64, end - chunk);
    int sv = 0;
    if (lane < m) {
      sv = csr_src[chunk + lane];
      float4 e = *(const float4*)&el2[sv * TT];
      float4 w;
      w.x = lrelu_exp(e.x + ern.x);
      w.y = lrelu_exp(e.y + ern.y);
      w.z = lrelu_exp(e.z + ern.z);
      w.w = lrelu_exp(e.w + ern.w);
      *(float4*)&myp[lane * 4] = w;
    }
    int j = 0;
    for (; j + 4 <= m; j += 4) {
      int s0 = __shfl(sv, j);
      int s1 = __shfl(sv, j + 1);
      int s2 = __shfl(sv, j + 2);
      int s3 = __shfl(sv, j + 3);
      float w0 = myp[(j + 0) * 4 + t];
      float w1 = myp[(j + 1) * 4 + t];
      float w2 = myp[(j + 2) * 4 + t];
      float w3 = myp[(j + 3) * 4 + t];
      float f0 = __half2float(feat2h[s0 * 64 + lane]);
      float f1 = __half2float(feat2h[s1 * 64 + lane]);
      float f2 = __half2float(feat2h[s2 * 64 + lane]);
      float f3 = __half2float(feat2h[s3 * 64 + lane]);
      l += (w0 + w1) + (w2 + w3);
      acc = fmaf(w0, f0, acc);
      acc = fmaf(w1, f1, acc);
      acc = fmaf(w2, f2, acc);
      acc = fmaf(w3, f3, acc);
    }
    for (; j < m; ++j) {
      int s0 = __shfl(sv, j);
      float w0 = myp[j * 4 + t];
      l += w0;
      acc = fmaf(w0, __half2float(feat2h[s0 * 64 + lane]), acc);
    }
  }
  float inv = (l > 0.f) ? (1.f / l) : 0.f;
  out[(n * TT + t) * OUT_F + f] = acc * inv + b2[f];
}

// ---------------------------------------------------------------------------
extern "C" void kernel_launch(void* const* d_in, const int* in_sizes, int n_in,
                              void* d_out, int out_size, void* d_ws, size_t ws_size,
                              hipStream_t stream) {
  const float* x   = (const float*)d_in[0];
  const int*   src = (const int*)d_in[1];
  const int*   dst = (const int*)d_in[2];
  const float* W1  = (const float*)d_in[3];
  const float* al1 = (const float*)d_in[4];
  const float* ar1 = (const float*)d_in[5];
  const float* b1  = (const float*)d_in[6];
  const float* W2  = (const float*)d_in[7];
  const float* al2 = (const float*)d_in[8];
  const float* ar2 = (const float*)d_in[9];
  const float* b2  = (const float*)d_in[10];
  float* out = (float*)d_out;

  // Workspace layout (bytes, 256-aligned chunks), ~72 MB total
  char* w = (char*)d_ws;
  float*  hbuf   = (float*)w;  w += (size_t)NT * C1 * 4;        // 40.96 MB
  float*  el1    = (float*)w;  w += (size_t)NT * H1 * 4;        // 2.56 MB
  float*  er1    = (float*)w;  w += (size_t)NT * H1 * 4;
  float*  el2    = (float*)w;  w += (size_t)NT * 4;             // 0.32 MB
  float*  er2    = (float*)w;  w += (size_t)NT * 4;
  __half* feat1h = (__half*)w; w += (size_t)NT * C1 * 2;        // 20.48 MB
  __half* feat2h = (__half*)w; w += (size_t)NT * OUT_F * 2;     // 2.56 MB
  int* counts  = (int*)w;      w += (size_t)NN * 4;
  int* offs    = (int*)w;      w += (size_t)(NN + 4) * 4;
  int* cursor  = (int*)w;      w += (size_t)NN * 4;
  int* csr_src = (int*)w;      w += (size_t)EE * 4;

  hipMemsetAsync(counts, 0, NN * sizeof(int), stream);

  k_feat1<<<NT / 16, 256, 0, stream>>>(x, W1, al1, ar1, feat1h, el1, er1);
  k_count<<<EE / 256, 256, 0, stream>>>(dst, counts);
  k_scan<<<1, 1024, 0, stream>>>(counts, offs, cursor);
  k_scatter<<<EE / 256, 256, 0, stream>>>(src, dst, cursor, csr_src);
  k_agg1<<<NN, 256, 0, stream>>>((const __half2*)feat1h, el1, er1, offs, csr_src, b1, hbuf);
  k_feat2<<<NT / 16, 256, 0, stream>>>(hbuf, W2, al2, ar2, feat2h, el2, er2);
  k_agg2<<<NN / 4, 256, 0, stream>>>(feat2h, el2, er2, offs, csr_src, b2, out);
}

// Round 5
// 225.774 us; speedup vs baseline: 1.6572x; 1.3421x over previous
//
#include <hip/hip_runtime.h>
#include <hip/hip_fp16.h>
#include <math.h>

// Problem constants (from reference)
#define NN 20000          // nodes
#define TT 4              // time steps
#define EE 320000         // edges
#define NT (NN*TT)        // 80000 rows
#define H1 8              // heads layer 1
#define C1 128            // heads*f_out layer 1
#define IN_F 32
#define OUT_F 16

typedef _Float16 h8 __attribute__((ext_vector_type(8)));
typedef float f32x4 __attribute__((ext_vector_type(4)));

__device__ __forceinline__ float lrelu_exp(float e) {
  e = (e >= 0.f) ? e : 0.2f * e;
  return __expf(e);
}

// ---------------------------------------------------------------------------
// Prep: pack W1 (+ fused attention cols) and W2 into MFMA B-fragment layout.
// B[k][n] lane layout: n = lane&15, k = (lane>>4)*8 + j  (8 halves/lane).
// W1p: 9 tiles (8 feature heads + 1 [Wl|Wr] tile).   [9][64][8] halves
// W2p: 8 tiles (4 k-steps feat + 4 k-steps [Wl2|Wr2|0]). [8][64][8] halves
// ---------------------------------------------------------------------------
__global__ __launch_bounds__(512) void k_prepw(
    const float* __restrict__ W1, const float* __restrict__ al1,
    const float* __restrict__ ar1, const float* __restrict__ W2,
    const float* __restrict__ al2, const float* __restrict__ ar2,
    __half* __restrict__ W1p, __half* __restrict__ W2p) {
  int tid = threadIdx.x;
  for (int idx = tid; idx < 9 * 512; idx += 512) {
    int tile = idx >> 9;
    int rem = idx & 511;
    int lane = rem >> 3, j = rem & 7;
    int k = (lane >> 4) * 8 + j;
    int n = lane & 15;
    float v;
    if (tile < 8) {
      v = W1[k * C1 + tile * 16 + n];
    } else {
      int hh = n & 7;
      const float* a = (n < 8) ? al1 : ar1;
      float s = 0.f;
      for (int f = 0; f < 16; ++f) s += W1[k * C1 + hh * 16 + f] * a[hh * 16 + f];
      v = s;
    }
    W1p[idx] = __float2half(v);
  }
  for (int idx = tid; idx < 8 * 512; idx += 512) {
    int tile = idx >> 9;
    int rem = idx & 511;
    int lane = rem >> 3, j = rem & 7;
    int ks = tile & 3;
    int k = ks * 32 + (lane >> 4) * 8 + j;
    int n = lane & 15;
    float v = 0.f;
    if (tile < 4) {
      v = W2[k * OUT_F + n];
    } else if (n == 0) {
      float s = 0.f;
      for (int f = 0; f < 16; ++f) s += W2[k * OUT_F + f] * al2[f];
      v = s;
    } else if (n == 1) {
      float s = 0.f;
      for (int f = 0; f < 16; ++f) s += W2[k * OUT_F + f] * ar2[f];
      v = s;
    }
    W2p[idx] = __float2half(v);
  }
}

// ---------------------------------------------------------------------------
// Pass A: feat1 = x @ W1 via MFMA 16x16x32 f16 (K=IN_F=32 in one mfma).
// Block = 4 waves, each wave one 16-row M-tile; 8 feat tiles + 1 el/er tile.
// ---------------------------------------------------------------------------
__global__ __launch_bounds__(256) void k_feat1(
    const float* __restrict__ x, const __half* __restrict__ W1p,
    __half* __restrict__ feat1h, float* __restrict__ el1, float* __restrict__ er1) {
  int tid = threadIdx.x;
  int wave = tid >> 6, lane = tid & 63;
  int m = lane & 15, quad = lane >> 4;
  int rowbase = blockIdx.x * 64 + wave * 16;
  int row = rowbase + m;
  // A frag: x[row][quad*8 .. quad*8+7], fp32 -> fp16
  const float4* xp = (const float4*)(x + row * IN_F + quad * 8);
  float4 a0 = xp[0], a1 = xp[1];
  h8 af;
  af[0] = (_Float16)a0.x; af[1] = (_Float16)a0.y;
  af[2] = (_Float16)a0.z; af[3] = (_Float16)a0.w;
  af[4] = (_Float16)a1.x; af[5] = (_Float16)a1.y;
  af[6] = (_Float16)a1.z; af[7] = (_Float16)a1.w;
  const h8* bp = (const h8*)W1p;
#pragma unroll
  for (int ht = 0; ht < 8; ++ht) {
    h8 bf = bp[ht * 64 + lane];
    f32x4 c = {0.f, 0.f, 0.f, 0.f};
    c = __builtin_amdgcn_mfma_f32_16x16x32_f16(af, bf, c, 0, 0, 0);
#pragma unroll
    for (int r = 0; r < 4; ++r)
      feat1h[(size_t)(rowbase + quad * 4 + r) * C1 + ht * 16 + m] = __float2half(c[r]);
  }
  {
    h8 bf = bp[8 * 64 + lane];
    f32x4 c = {0.f, 0.f, 0.f, 0.f};
    c = __builtin_amdgcn_mfma_f32_16x16x32_f16(af, bf, c, 0, 0, 0);
#pragma unroll
    for (int r = 0; r < 4; ++r) {
      int orow = rowbase + quad * 4 + r;
      if (m < 8) el1[orow * H1 + m] = c[r];
      else       er1[orow * H1 + (m - 8)] = c[r];
    }
  }
}

// ---------------------------------------------------------------------------
// CSR build: counts -> exclusive scan -> scatter (src in CSR order)
// ---------------------------------------------------------------------------
__global__ void k_count(const int* __restrict__ dst, int* __restrict__ counts) {
  int e = blockIdx.x * 256 + threadIdx.x;
  if (e < EE) atomicAdd(&counts[dst[e]], 1);
}

__global__ __launch_bounds__(1024) void k_scan(
    const int* __restrict__ counts, int* __restrict__ offs,
    int* __restrict__ cursor) {
  __shared__ int sums[1024];
  int tid = threadIdx.x;
  int base = tid * 20;
  int local[20];
  int run = 0;
#pragma unroll
  for (int j = 0; j < 20; ++j) {
    int i = base + j;
    int v = (i < NN) ? counts[i] : 0;
    local[j] = run;                   // exclusive prefix within thread
    run += v;
  }
  sums[tid] = run;
  __syncthreads();
  int val = run;
#pragma unroll
  for (int off = 1; off < 1024; off <<= 1) {
    int add = (tid >= off) ? sums[tid - off] : 0;
    __syncthreads();
    val += add;
    sums[tid] = val;
    __syncthreads();
  }
  int excl = val - run;
#pragma unroll
  for (int j = 0; j < 20; ++j) {
    int i = base + j;
    if (i < NN) {
      int o = excl + local[j];
      offs[i] = o;
      cursor[i] = o;
    }
  }
  if (tid == 1023) offs[NN] = val;    // == EE
}

__global__ void k_scatter(const int* __restrict__ src, const int* __restrict__ dst,
                          int* __restrict__ cursor, int* __restrict__ csr_src) {
  int e = blockIdx.x * 256 + threadIdx.x;
  if (e < EE) {
    int d = dst[e];
    int pos = atomicAdd(&cursor[d], 1);
    csr_src[pos] = src[e];
  }
}

// ---------------------------------------------------------------------------
// Pass C: layer-1 softmax-aggregate. One block per dst node; 256 threads =
// 4 waves (one per t), lane handles channels {2*lane, 2*lane+1} (fp16x2).
// Wave-private LDS weight tile; h output stored fp16 for the MFMA layer 2.
// ---------------------------------------------------------------------------
__global__ __launch_bounds__(256) void k_agg1(
    const __half2* __restrict__ feat1h2,   // [NT][64] half2
    const float* __restrict__ el1, const float* __restrict__ er1,
    const int* __restrict__ offs, const int* __restrict__ csr_src,
    const float* __restrict__ b1, __half2* __restrict__ hh2) {
  __shared__ float plds[4][64][8];         // 8 KB, wave-private slabs
  int n = blockIdx.x;
  int tid = threadIdx.x;
  int t = tid >> 6;                        // wave id == t
  int lane = tid & 63;
  int hh = lane >> 3;                      // head for this lane's channel pair
  int beg = offs[n], end = offs[n + 1];
  float4 erA = *(const float4*)&er1[(n * TT + t) * H1];
  float4 erB = *(const float4*)&er1[(n * TT + t) * H1 + 4];
  float* myp = &plds[t][0][0];
  float l = 0.f;
  float accx = 0.f, accy = 0.f;
  for (int chunk = beg; chunk < end; chunk += 64) {
    int m = min(64, end - chunk);
    int sv = 0;
    if (lane < m) {
      sv = csr_src[chunk + lane];
      const float4* e4 = (const float4*)&el1[(sv * TT + t) * H1];
      float4 ea = e4[0], eb = e4[1];
      float4 w0, w1;
      w0.x = lrelu_exp(ea.x + erA.x);
      w0.y = lrelu_exp(ea.y + erA.y);
      w0.z = lrelu_exp(ea.z + erA.z);
      w0.w = lrelu_exp(ea.w + erA.w);
      w1.x = lrelu_exp(eb.x + erB.x);
      w1.y = lrelu_exp(eb.y + erB.y);
      w1.z = lrelu_exp(eb.z + erB.z);
      w1.w = lrelu_exp(eb.w + erB.w);
      *(float4*)&myp[lane * 8]     = w0;
      *(float4*)&myp[lane * 8 + 4] = w1;
    }
    int j = 0;
    for (; j + 4 <= m; j += 4) {
      int s0 = __shfl(sv, j);
      int s1 = __shfl(sv, j + 1);
      int s2 = __shfl(sv, j + 2);
      int s3 = __shfl(sv, j + 3);
      float w0 = myp[(j + 0) * 8 + hh];
      float w1 = myp[(j + 1) * 8 + hh];
      float w2 = myp[(j + 2) * 8 + hh];
      float w3 = myp[(j + 3) * 8 + hh];
      __half2 f0 = feat1h2[(s0 * TT + t) * 64 + lane];
      __half2 f1 = feat1h2[(s1 * TT + t) * 64 + lane];
      __half2 f2 = feat1h2[(s2 * TT + t) * 64 + lane];
      __half2 f3 = feat1h2[(s3 * TT + t) * 64 + lane];
      float2 g0 = __half22float2(f0);
      float2 g1 = __half22float2(f1);
      float2 g2 = __half22float2(f2);
      float2 g3 = __half22float2(f3);
      l += (w0 + w1) + (w2 + w3);
      accx = fmaf(w0, g0.x, accx); accy = fmaf(w0, g0.y, accy);
      accx = fmaf(w1, g1.x, accx); accy = fmaf(w1, g1.y, accy);
      accx = fmaf(w2, g2.x, accx); accy = fmaf(w2, g2.y, accy);
      accx = fmaf(w3, g3.x, accx); accy = fmaf(w3, g3.y, accy);
    }
    for (; j < m; ++j) {
      int s0 = __shfl(sv, j);
      float w0 = myp[j * 8 + hh];
      float2 g0 = __half22float2(feat1h2[(s0 * TT + t) * 64 + lane]);
      l += w0;
      accx = fmaf(w0, g0.x, accx);
      accy = fmaf(w0, g0.y, accy);
    }
  }
  float inv = (l > 0.f) ? (1.f / l) : 0.f;
  float2 bv = *(const float2*)&b1[2 * lane];
  float2 r;
  r.x = accx * inv + bv.x;
  r.y = accy * inv + bv.y;
  hh2[(n * TT + t) * 64 + lane] = __float22half2_rn(r);
}

// ---------------------------------------------------------------------------
// Pass D: feat2 = h @ W2 via MFMA; el2/er2 fused as a second B-tile.
// Block = 4 waves x 16-row tiles; h read as fp16 (written by k_agg1).
// ---------------------------------------------------------------------------
__global__ __launch_bounds__(256) void k_feat2(
    const __half* __restrict__ hh, const __half* __restrict__ W2p,
    __half* __restrict__ feat2h, float* __restrict__ el2, float* __restrict__ er2) {
  int tid = threadIdx.x;
  int wave = tid >> 6, lane = tid & 63;
  int m = lane & 15, quad = lane >> 4;
  int rowbase = blockIdx.x * 64 + wave * 16;
  const h8* hp = (const h8*)hh;          // [row][16] h8 chunks
  const h8* bp = (const h8*)W2p;
  f32x4 cF = {0.f, 0.f, 0.f, 0.f};
  f32x4 cE = {0.f, 0.f, 0.f, 0.f};
#pragma unroll
  for (int ks = 0; ks < 4; ++ks) {
    h8 af = hp[(size_t)(rowbase + m) * 16 + ks * 4 + quad];
    cF = __builtin_amdgcn_mfma_f32_16x16x32_f16(af, bp[ks * 64 + lane], cF, 0, 0, 0);
    cE = __builtin_amdgcn_mfma_f32_16x16x32_f16(af, bp[(4 + ks) * 64 + lane], cE, 0, 0, 0);
  }
#pragma unroll
  for (int r = 0; r < 4; ++r) {
    int orow = rowbase + quad * 4 + r;
    feat2h[(size_t)orow * OUT_F + m] = __float2half(cF[r]);
    if (m == 0) el2[orow] = cE[r];
    if (m == 1) er2[orow] = cE[r];
  }
}

// ---------------------------------------------------------------------------
// Pass E: layer-2 aggregate. 4 nodes per 256-thread block; one wave per node
// = (t,f) = (4,16). Wave-private LDS weight scheme.
// ---------------------------------------------------------------------------
__global__ __launch_bounds__(256) void k_agg2(
    const __half* __restrict__ feat2h,     // [NT][16] = [s][64 halves]
    const float* __restrict__ el2, const float* __restrict__ er2,
    const int* __restrict__ offs, const int* __restrict__ csr_src,
    const float* __restrict__ b2, float* __restrict__ out) {
  __shared__ float plds[4][64][4];         // 4 KB, wave-private slabs
  int tid = threadIdx.x;
  int nb = tid >> 6;
  int n = blockIdx.x * 4 + nb;
  int lane = tid & 63, t = lane >> 4, f = lane & 15;
  int beg = offs[n], end = offs[n + 1];
  float4 ern = *(const float4*)&er2[n * TT];
  float* myp = &plds[nb][0][0];
  float l = 0.f, acc = 0.f;
  for (int chunk = beg; chunk < end; chunk += 64) {
    int m = min(64, end - chunk);
    int sv = 0;
    if (lane < m) {
      sv = csr_src[chunk + lane];
      float4 e = *(const float4*)&el2[sv * TT];
      float4 w;
      w.x = lrelu_exp(e.x + ern.x);
      w.y = lrelu_exp(e.y + ern.y);
      w.z = lrelu_exp(e.z + ern.z);
      w.w = lrelu_exp(e.w + ern.w);
      *(float4*)&myp[lane * 4] = w;
    }
    int j = 0;
    for (; j + 4 <= m; j += 4) {
      int s0 = __shfl(sv, j);
      int s1 = __shfl(sv, j + 1);
      int s2 = __shfl(sv, j + 2);
      int s3 = __shfl(sv, j + 3);
      float w0 = myp[(j + 0) * 4 + t];
      float w1 = myp[(j + 1) * 4 + t];
      float w2 = myp[(j + 2) * 4 + t];
      float w3 = myp[(j + 3) * 4 + t];
      float f0 = __half2float(feat2h[s0 * 64 + lane]);
      float f1 = __half2float(feat2h[s1 * 64 + lane]);
      float f2 = __half2float(feat2h[s2 * 64 + lane]);
      float f3 = __half2float(feat2h[s3 * 64 + lane]);
      l += (w0 + w1) + (w2 + w3);
      acc = fmaf(w0, f0, acc);
      acc = fmaf(w1, f1, acc);
      acc = fmaf(w2, f2, acc);
      acc = fmaf(w3, f3, acc);
    }
    for (; j < m; ++j) {
      int s0 = __shfl(sv, j);
      float w0 = myp[j * 4 + t];
      l += w0;
      acc = fmaf(w0, __half2float(feat2h[s0 * 64 + lane]), acc);
    }
  }
  float inv = (l > 0.f) ? (1.f / l) : 0.f;
  out[(n * TT + t) * OUT_F + f] = acc * inv + b2[f];
}

// ---------------------------------------------------------------------------
extern "C" void kernel_launch(void* const* d_in, const int* in_sizes, int n_in,
                              void* d_out, int out_size, void* d_ws, size_t ws_size,
                              hipStream_t stream) {
  const float* x   = (const float*)d_in[0];
  const int*   src = (const int*)d_in[1];
  const int*   dst = (const int*)d_in[2];
  const float* W1  = (const float*)d_in[3];
  const float* al1 = (const float*)d_in[4];
  const float* ar1 = (const float*)d_in[5];
  const float* b1  = (const float*)d_in[6];
  const float* W2  = (const float*)d_in[7];
  const float* al2 = (const float*)d_in[8];
  const float* ar2 = (const float*)d_in[9];
  const float* b2  = (const float*)d_in[10];
  float* out = (float*)d_out;

  // Workspace layout (bytes, 256-aligned chunks), ~52 MB total
  char* w = (char*)d_ws;
  __half* feat1h = (__half*)w; w += (size_t)NT * C1 * 2;        // 20.48 MB
  __half* hh     = (__half*)w; w += (size_t)NT * C1 * 2;        // 20.48 MB
  __half* feat2h = (__half*)w; w += (size_t)NT * OUT_F * 2;     // 2.56 MB
  float*  el1    = (float*)w;  w += (size_t)NT * H1 * 4;        // 2.56 MB
  float*  er1    = (float*)w;  w += (size_t)NT * H1 * 4;
  float*  el2    = (float*)w;  w += (size_t)NT * 4;             // 0.32 MB
  float*  er2    = (float*)w;  w += (size_t)NT * 4;
  __half* W1p    = (__half*)w; w += (size_t)9 * 512 * 2;
  __half* W2p    = (__half*)w; w += (size_t)8 * 512 * 2;
  int* counts  = (int*)w;      w += (size_t)NN * 4;
  int* offs    = (int*)w;      w += (size_t)(NN + 4) * 4;
  int* cursor  = (int*)w;      w += (size_t)NN * 4;
  int* csr_src = (int*)w;      w += (size_t)EE * 4;

  hipMemsetAsync(counts, 0, NN * sizeof(int), stream);

  k_prepw<<<1, 512, 0, stream>>>(W1, al1, ar1, W2, al2, ar2, W1p, W2p);
  k_feat1<<<NT / 64, 256, 0, stream>>>(x, W1p, feat1h, el1, er1);
  k_count<<<EE / 256, 256, 0, stream>>>(dst, counts);
  k_scan<<<1, 1024, 0, stream>>>(counts, offs, cursor);
  k_scatter<<<EE / 256, 256, 0, stream>>>(src, dst, cursor, csr_src);
  k_agg1<<<NN, 256, 0, stream>>>((const __half2*)feat1h, el1, er1, offs, csr_src,
                                 b1, (__half2*)hh);
  k_feat2<<<NT / 64, 256, 0, stream>>>(hh, W2p, feat2h, el2, er2);
  k_agg2<<<NN / 4, 256, 0, stream>>>(feat2h, el2, er2, offs, csr_src, b2, out);
}

// Round 6
// 223.513 us; speedup vs baseline: 1.6739x; 1.0101x over previous
//
#include <hip/hip_runtime.h>
#include <hip/hip_fp16.h>
#include <math.h>

// Problem constants (from reference)
#define NN 20000          // nodes
#define TT 4              // time steps
#define EE 320000         // edges
#define NT (NN*TT)        // 80000 rows
#define H1 8              // heads layer 1
#define C1 128            // heads*f_out layer 1
#define IN_F 32
#define OUT_F 16

typedef _Float16 h8 __attribute__((ext_vector_type(8)));
typedef float f32x4 __attribute__((ext_vector_type(4)));

__device__ __forceinline__ float lrelu_exp(float e) {
  e = (e >= 0.f) ? e : 0.2f * e;
  return __expf(e);
}

// ---------------------------------------------------------------------------
// k_count (+ fused weight-prep on block 0): int4-vectorized degree count.
// Prep packs W1/W2 (+ fused attention dot columns) into MFMA B-frag layout.
// ---------------------------------------------------------------------------
__global__ __launch_bounds__(256) void k_count_prep(
    const int4* __restrict__ dst4, int* __restrict__ counts,
    const float* __restrict__ W1, const float* __restrict__ al1,
    const float* __restrict__ ar1, const float* __restrict__ W2,
    const float* __restrict__ al2, const float* __restrict__ ar2,
    __half* __restrict__ W1p, __half* __restrict__ W2p) {
  int tid = threadIdx.x;
  int e4 = blockIdx.x * 256 + tid;
  if (e4 < EE / 4) {
    int4 d = dst4[e4];
    atomicAdd(&counts[d.x], 1);
    atomicAdd(&counts[d.y], 1);
    atomicAdd(&counts[d.z], 1);
    atomicAdd(&counts[d.w], 1);
  }
  if (blockIdx.x == 0) {
    for (int idx = tid; idx < 9 * 512; idx += 256) {
      int tile = idx >> 9;
      int rem = idx & 511;
      int lane = rem >> 3, j = rem & 7;
      int k = (lane >> 4) * 8 + j;
      int n = lane & 15;
      float v;
      if (tile < 8) {
        v = W1[k * C1 + tile * 16 + n];
      } else {
        int hh = n & 7;
        const float* a = (n < 8) ? al1 : ar1;
        float s = 0.f;
        for (int f = 0; f < 16; ++f) s += W1[k * C1 + hh * 16 + f] * a[hh * 16 + f];
        v = s;
      }
      W1p[idx] = __float2half(v);
    }
    for (int idx = tid; idx < 8 * 512; idx += 256) {
      int tile = idx >> 9;
      int rem = idx & 511;
      int lane = rem >> 3, j = rem & 7;
      int ks = tile & 3;
      int k = ks * 32 + (lane >> 4) * 8 + j;
      int n = lane & 15;
      float v = 0.f;
      if (tile < 4) {
        v = W2[k * OUT_F + n];
      } else if (n == 0) {
        float s = 0.f;
        for (int f = 0; f < 16; ++f) s += W2[k * OUT_F + f] * al2[f];
        v = s;
      } else if (n == 1) {
        float s = 0.f;
        for (int f = 0; f < 16; ++f) s += W2[k * OUT_F + f] * ar2[f];
        v = s;
      }
      W2p[idx] = __float2half(v);
    }
  }
}

__global__ __launch_bounds__(1024) void k_scan(
    const int* __restrict__ counts, int* __restrict__ offs,
    int* __restrict__ cursor) {
  __shared__ int sums[1024];
  int tid = threadIdx.x;
  int base = tid * 20;
  int local[20];
  int run = 0;
#pragma unroll
  for (int j = 0; j < 20; ++j) {
    int i = base + j;
    int v = (i < NN) ? counts[i] : 0;
    local[j] = run;                   // exclusive prefix within thread
    run += v;
  }
  sums[tid] = run;
  __syncthreads();
  int val = run;
#pragma unroll
  for (int off = 1; off < 1024; off <<= 1) {
    int add = (tid >= off) ? sums[tid - off] : 0;
    __syncthreads();
    val += add;
    sums[tid] = val;
    __syncthreads();
  }
  int excl = val - run;
#pragma unroll
  for (int j = 0; j < 20; ++j) {
    int i = base + j;
    if (i < NN) {
      int o = excl + local[j];
      offs[i] = o;
      cursor[i] = o;
    }
  }
  if (tid == 1023) offs[NN] = val;    // == EE
}

__global__ __launch_bounds__(256) void k_scatter(
    const int4* __restrict__ src4, const int4* __restrict__ dst4,
    int* __restrict__ cursor, int* __restrict__ csr_src) {
  int e4 = blockIdx.x * 256 + threadIdx.x;
  if (e4 < EE / 4) {
    int4 s = src4[e4];
    int4 d = dst4[e4];
    int p0 = atomicAdd(&cursor[d.x], 1); csr_src[p0] = s.x;
    int p1 = atomicAdd(&cursor[d.y], 1); csr_src[p1] = s.y;
    int p2 = atomicAdd(&cursor[d.z], 1); csr_src[p2] = s.z;
    int p3 = atomicAdd(&cursor[d.w], 1); csr_src[p3] = s.w;
  }
}

// ---------------------------------------------------------------------------
// Pass A: feat1 = x @ W1 via MFMA 16x16x32 f16. Outputs stored T-MAJOR:
// feat1h_t[t][n][128], el1_t/er1_t[t][n][8] — so k_agg1's per-t waves stream
// a 5.1 MB slice instead of the interleaved 20.5 MB array.
// ---------------------------------------------------------------------------
__global__ __launch_bounds__(256) void k_feat1(
    const float* __restrict__ x, const __half* __restrict__ W1p,
    __half* __restrict__ feat1h_t, float* __restrict__ el1_t,
    float* __restrict__ er1_t) {
  int tid = threadIdx.x;
  int wave = tid >> 6, lane = tid & 63;
  int m = lane & 15, quad = lane >> 4;
  int rowbase = blockIdx.x * 64 + wave * 16;
  int row = rowbase + m;
  const float4* xp = (const float4*)(x + row * IN_F + quad * 8);
  float4 a0 = xp[0], a1 = xp[1];
  h8 af;
  af[0] = (_Float16)a0.x; af[1] = (_Float16)a0.y;
  af[2] = (_Float16)a0.z; af[3] = (_Float16)a0.w;
  af[4] = (_Float16)a1.x; af[5] = (_Float16)a1.y;
  af[6] = (_Float16)a1.z; af[7] = (_Float16)a1.w;
  const h8* bp = (const h8*)W1p;
#pragma unroll
  for (int ht = 0; ht < 8; ++ht) {
    h8 bf = bp[ht * 64 + lane];
    f32x4 c = {0.f, 0.f, 0.f, 0.f};
    c = __builtin_amdgcn_mfma_f32_16x16x32_f16(af, bf, c, 0, 0, 0);
#pragma unroll
    for (int r = 0; r < 4; ++r) {
      int orow = rowbase + quad * 4 + r;
      int n2 = orow >> 2, t2 = orow & 3;
      feat1h_t[((size_t)t2 * NN + n2) * C1 + ht * 16 + m] = __float2half(c[r]);
    }
  }
  {
    h8 bf = bp[8 * 64 + lane];
    f32x4 c = {0.f, 0.f, 0.f, 0.f};
    c = __builtin_amdgcn_mfma_f32_16x16x32_f16(af, bf, c, 0, 0, 0);
#pragma unroll
    for (int r = 0; r < 4; ++r) {
      int orow = rowbase + quad * 4 + r;
      int n2 = orow >> 2, t2 = orow & 3;
      if (m < 8) el1_t[((size_t)t2 * NN + n2) * H1 + m] = c[r];
      else       er1_t[((size_t)t2 * NN + n2) * H1 + (m - 8)] = c[r];
    }
  }
}

// ---------------------------------------------------------------------------
// Pass C: layer-1 softmax-aggregate, XCD-sliced by t.
// Block = 4 waves = 4 nodes, ALL SAME t; t tied to XCD via blockIdx&7
// (block->XCD is round-robin %8), so each XCD-pair's L2 holds one t-slice.
// ---------------------------------------------------------------------------
__global__ __launch_bounds__(256) void k_agg1(
    const __half2* __restrict__ feat1h2_t,   // [t][NN][64] half2
    const float* __restrict__ el1_t, const float* __restrict__ er1_t,
    const int* __restrict__ offs, const int* __restrict__ csr_src,
    const float* __restrict__ b1, __half2* __restrict__ hh2) {
  __shared__ float plds[4][64][8];           // 8 KB, wave-private slabs
  int b = blockIdx.x;
  int xcd = b & 7;
  int t = xcd >> 1;
  int par = xcd & 1;
  int grp = b >> 3;                          // 0..2499
  int tid = threadIdx.x;
  int w = tid >> 6;                          // wave id
  int lane = tid & 63;
  int n = grp * 8 + par * 4 + w;             // node for this wave
  int hh = lane >> 3;                        // head for this lane's channel pair
  int beg = offs[n], end = offs[n + 1];
  const __half2* fbase = feat1h2_t + (size_t)t * NN * 64;
  const float* elb = el1_t + (size_t)t * NN * H1;
  const float* erb = er1_t + (size_t)t * NN * H1;
  float4 erA = *(const float4*)&erb[n * H1];
  float4 erB = *(const float4*)&erb[n * H1 + 4];
  float* myp = &plds[w][0][0];
  float l = 0.f;
  float accx = 0.f, accy = 0.f;
  for (int chunk = beg; chunk < end; chunk += 64) {
    int m = min(64, end - chunk);
    int sv = 0;
    if (lane < m) {
      sv = csr_src[chunk + lane];
      const float4* e4 = (const float4*)&elb[sv * H1];
      float4 ea = e4[0], eb = e4[1];
      float4 w0, w1;
      w0.x = lrelu_exp(ea.x + erA.x);
      w0.y = lrelu_exp(ea.y + erA.y);
      w0.z = lrelu_exp(ea.z + erA.z);
      w0.w = lrelu_exp(ea.w + erA.w);
      w1.x = lrelu_exp(eb.x + erB.x);
      w1.y = lrelu_exp(eb.y + erB.y);
      w1.z = lrelu_exp(eb.z + erB.z);
      w1.w = lrelu_exp(eb.w + erB.w);
      *(float4*)&myp[lane * 8]     = w0;
      *(float4*)&myp[lane * 8 + 4] = w1;
    }
    // wave-private LDS slab: same-wave DS ordering suffices, no barrier
    int j = 0;
    for (; j + 4 <= m; j += 4) {
      int s0 = __shfl(sv, j);
      int s1 = __shfl(sv, j + 1);
      int s2 = __shfl(sv, j + 2);
      int s3 = __shfl(sv, j + 3);
      float w0 = myp[(j + 0) * 8 + hh];
      float w1 = myp[(j + 1) * 8 + hh];
      float w2 = myp[(j + 2) * 8 + hh];
      float w3 = myp[(j + 3) * 8 + hh];
      __half2 f0 = fbase[s0 * 64 + lane];
      __half2 f1 = fbase[s1 * 64 + lane];
      __half2 f2 = fbase[s2 * 64 + lane];
      __half2 f3 = fbase[s3 * 64 + lane];
      float2 g0 = __half22float2(f0);
      float2 g1 = __half22float2(f1);
      float2 g2 = __half22float2(f2);
      float2 g3 = __half22float2(f3);
      l += (w0 + w1) + (w2 + w3);
      accx = fmaf(w0, g0.x, accx); accy = fmaf(w0, g0.y, accy);
      accx = fmaf(w1, g1.x, accx); accy = fmaf(w1, g1.y, accy);
      accx = fmaf(w2, g2.x, accx); accy = fmaf(w2, g2.y, accy);
      accx = fmaf(w3, g3.x, accx); accy = fmaf(w3, g3.y, accy);
    }
    for (; j < m; ++j) {
      int s0 = __shfl(sv, j);
      float w0 = myp[j * 8 + hh];
      float2 g0 = __half22float2(fbase[s0 * 64 + lane]);
      l += w0;
      accx = fmaf(w0, g0.x, accx);
      accy = fmaf(w0, g0.y, accy);
    }
  }
  float inv = (l > 0.f) ? (1.f / l) : 0.f;
  float2 bv = *(const float2*)&b1[2 * lane];
  float2 r;
  r.x = accx * inv + bv.x;
  r.y = accy * inv + bv.y;
  hh2[(n * TT + t) * 64 + lane] = __float22half2_rn(r);
}

// ---------------------------------------------------------------------------
// Pass D: feat2 = h @ W2 via MFMA; el2/er2 fused as a second B-tile.
// ---------------------------------------------------------------------------
__global__ __launch_bounds__(256) void k_feat2(
    const __half* __restrict__ hh, const __half* __restrict__ W2p,
    __half* __restrict__ feat2h, float* __restrict__ el2, float* __restrict__ er2) {
  int tid = threadIdx.x;
  int wave = tid >> 6, lane = tid & 63;
  int m = lane & 15, quad = lane >> 4;
  int rowbase = blockIdx.x * 64 + wave * 16;
  const h8* hp = (const h8*)hh;          // [row][16] h8 chunks
  const h8* bp = (const h8*)W2p;
  f32x4 cF = {0.f, 0.f, 0.f, 0.f};
  f32x4 cE = {0.f, 0.f, 0.f, 0.f};
#pragma unroll
  for (int ks = 0; ks < 4; ++ks) {
    h8 af = hp[(size_t)(rowbase + m) * 16 + ks * 4 + quad];
    cF = __builtin_amdgcn_mfma_f32_16x16x32_f16(af, bp[ks * 64 + lane], cF, 0, 0, 0);
    cE = __builtin_amdgcn_mfma_f32_16x16x32_f16(af, bp[(4 + ks) * 64 + lane], cE, 0, 0, 0);
  }
#pragma unroll
  for (int r = 0; r < 4; ++r) {
    int orow = rowbase + quad * 4 + r;
    feat2h[(size_t)orow * OUT_F + m] = __float2half(cF[r]);
    if (m == 0) el2[orow] = cE[r];
    if (m == 1) er2[orow] = cE[r];
  }
}

// ---------------------------------------------------------------------------
// Pass E: layer-2 aggregate. 4 nodes per 256-thread block; one wave per node
// = (t,f) = (4,16). Wave-private LDS weight scheme. feat2h working set is
// 2.56 MB -> L2-resident, no restructure needed.
// ---------------------------------------------------------------------------
__global__ __launch_bounds__(256) void k_agg2(
    const __half* __restrict__ feat2h,     // [s][64 halves] = full (t,f) block
    const float* __restrict__ el2, const float* __restrict__ er2,
    const int* __restrict__ offs, const int* __restrict__ csr_src,
    const float* __restrict__ b2, float* __restrict__ out) {
  __shared__ float plds[4][64][4];         // 4 KB, wave-private slabs
  int tid = threadIdx.x;
  int nb = tid >> 6;
  int n = blockIdx.x * 4 + nb;
  int lane = tid & 63, t = lane >> 4, f = lane & 15;
  int beg = offs[n], end = offs[n + 1];
  float4 ern = *(const float4*)&el2[0];    // placeholder overwritten below
  ern = *(const float4*)&er2[n * TT];
  float* myp = &plds[nb][0][0];
  float l = 0.f, acc = 0.f;
  for (int chunk = beg; chunk < end; chunk += 64) {
    int m = min(64, end - chunk);
    int sv = 0;
    if (lane < m) {
      sv = csr_src[chunk + lane];
      float4 e = *(const float4*)&el2[sv * TT];
      float4 w;
      w.x = lrelu_exp(e.x + ern.x);
      w.y = lrelu_exp(e.y + ern.y);
      w.z = lrelu_exp(e.z + ern.z);
      w.w = lrelu_exp(e.w + ern.w);
      *(float4*)&myp[lane * 4] = w;
    }
    int j = 0;
    for (; j + 4 <= m; j += 4) {
      int s0 = __shfl(sv, j);
      int s1 = __shfl(sv, j + 1);
      int s2 = __shfl(sv, j + 2);
      int s3 = __shfl(sv, j + 3);
      float w0 = myp[(j + 0) * 4 + t];
      float w1 = myp[(j + 1) * 4 + t];
      float w2 = myp[(j + 2) * 4 + t];
      float w3 = myp[(j + 3) * 4 + t];
      float f0 = __half2float(feat2h[s0 * 64 + lane]);
      float f1 = __half2float(feat2h[s1 * 64 + lane]);
      float f2 = __half2float(feat2h[s2 * 64 + lane]);
      float f3 = __half2float(feat2h[s3 * 64 + lane]);
      l += (w0 + w1) + (w2 + w3);
      acc = fmaf(w0, f0, acc);
      acc = fmaf(w1, f1, acc);
      acc = fmaf(w2, f2, acc);
      acc = fmaf(w3, f3, acc);
    }
    for (; j < m; ++j) {
      int s0 = __shfl(sv, j);
      float w0 = myp[j * 4 + t];
      l += w0;
      acc = fmaf(w0, __half2float(feat2h[s0 * 64 + lane]), acc);
    }
  }
  float inv = (l > 0.f) ? (1.f / l) : 0.f;
  out[(n * TT + t) * OUT_F + f] = acc * inv + b2[f];
}

// ---------------------------------------------------------------------------
extern "C" void kernel_launch(void* const* d_in, const int* in_sizes, int n_in,
                              void* d_out, int out_size, void* d_ws, size_t ws_size,
                              hipStream_t stream) {
  const float* x   = (const float*)d_in[0];
  const int*   src = (const int*)d_in[1];
  const int*   dst = (const int*)d_in[2];
  const float* W1  = (const float*)d_in[3];
  const float* al1 = (const float*)d_in[4];
  const float* ar1 = (const float*)d_in[5];
  const float* b1  = (const float*)d_in[6];
  const float* W2  = (const float*)d_in[7];
  const float* al2 = (const float*)d_in[8];
  const float* ar2 = (const float*)d_in[9];
  const float* b2  = (const float*)d_in[10];
  float* out = (float*)d_out;

  // Workspace layout (bytes, 256-aligned chunks), ~52 MB total
  char* w = (char*)d_ws;
  __half* feat1h = (__half*)w; w += (size_t)NT * C1 * 2;        // 20.48 MB (t-major)
  __half* hh     = (__half*)w; w += (size_t)NT * C1 * 2;        // 20.48 MB
  __half* feat2h = (__half*)w; w += (size_t)NT * OUT_F * 2;     // 2.56 MB
  float*  el1    = (float*)w;  w += (size_t)NT * H1 * 4;        // 2.56 MB (t-major)
  float*  er1    = (float*)w;  w += (size_t)NT * H1 * 4;        //          (t-major)
  float*  el2    = (float*)w;  w += (size_t)NT * 4;             // 0.32 MB
  float*  er2    = (float*)w;  w += (size_t)NT * 4;
  __half* W1p    = (__half*)w; w += (size_t)9 * 512 * 2;
  __half* W2p    = (__half*)w; w += (size_t)8 * 512 * 2;
  int* counts  = (int*)w;      w += (size_t)NN * 4;
  int* offs    = (int*)w;      w += (size_t)(NN + 4) * 4;
  int* cursor  = (int*)w;      w += (size_t)NN * 4;
  int* csr_src = (int*)w;      w += (size_t)EE * 4;

  hipMemsetAsync(counts, 0, NN * sizeof(int), stream);

  k_count_prep<<<(EE / 4 + 255) / 256, 256, 0, stream>>>(
      (const int4*)dst, counts, W1, al1, ar1, W2, al2, ar2, W1p, W2p);
  k_scan<<<1, 1024, 0, stream>>>(counts, offs, cursor);
  k_scatter<<<(EE / 4 + 255) / 256, 256, 0, stream>>>(
      (const int4*)src, (const int4*)dst, cursor, csr_src);
  k_feat1<<<NT / 64, 256, 0, stream>>>(x, W1p, feat1h, el1, er1);
  k_agg1<<<NN, 256, 0, stream>>>((const __half2*)feat1h, el1, er1, offs, csr_src,
                                 b1, (__half2*)hh);
  k_feat2<<<NT / 64, 256, 0, stream>>>(hh, W2p, feat2h, el2, er2);
  k_agg2<<<NN / 4, 256, 0, stream>>>(feat2h, el2, er2, offs, csr_src, b2, out);
}